// Round 2
// 697.080 us; speedup vs baseline: 1.1929x; 1.1929x over previous
//
#include <hip/hip_runtime.h>

#define WIDTH 4096
#define HALF  2048
#define DEPTH 32
#define BATCH 16384
#define NROWS 4
#define NTH   256
#define LDS_STRIDE 4736   // max pad_addr(4095)=4723, round up to /16

#define LAY_H  0
#define LAY_M  1
#define LAY_L  2
#define LAY_MP 3

__device__ __forceinline__ int pad_addr(int q) {
    // bank-conflict swizzle: H free, M 2-way, L(b128) optimal
    return q + 4 * (q >> 5) + 8 * (q >> 8);
}

__device__ __forceinline__ int ror12f(int q, int k) {
    // rotate-right of a 12-bit value by k (1..12)
    return ((q >> k) | (q << (12 - k))) & 4095;
}

template<int LA>
__device__ __forceinline__ int lay_q(int t, int v) {
    if constexpr (LA == LAY_H)       return (v << 8) | t;
    else if constexpr (LA == LAY_M)  return ((t & 0xF0) << 4) | (v << 4) | (t & 15);
    else if constexpr (LA == LAY_L)  return (t << 4) | v;
    else /* MP: round-7 layout; output col p = 16t + v */
                                     return ((t & 15) << 8) | (v << 4) | (t >> 4);
}

// 4 stages fully in registers. The angle table has been PRE-PERMUTED by
// cs_kernel so that the value needed by (stage s, thread t, pair h) sits at
// cs[(s<<11) | (h<<8) | t]  -> all reads are lane-coalesced dwordx2.
template<int LA, int S0>
__device__ __forceinline__ void do_round(float (&x)[NROWS][16], int t,
                                         const float2* __restrict__ cs) {
    #pragma unroll
    for (int j = 0; j < 4; ++j) {
        const int s  = S0 + j;
        const int jb = 3 - j;        // partner bit within the nibble
        const float2* __restrict__ pcs = cs + (s << 11) + t;
        float2 w[8];
        #pragma unroll
        for (int h = 0; h < 8; ++h)
            w[h] = pcs[h << 8];      // coalesced: lane t reads base+8*t
        #pragma unroll
        for (int h = 0; h < 8; ++h) {
            const int v0 = ((h >> jb) << (jb + 1)) | (h & ((1 << jb) - 1));
            const int v1 = v0 | (1 << jb);
            const float c = w[h].x, sn = w[h].y;
            #pragma unroll
            for (int rr = 0; rr < NROWS; ++rr) {
                const float x0 = x[rr][v0];
                const float x1 = x[rr][v1];
                x[rr][v0] = fmaf(x0, c,  x1 * sn);   // y0 =  c*x0 + s*x1
                x[rr][v1] = fmaf(x1, c, -x0 * sn);   // y1 = -s*x0 + c*x1
            }
        }
    }
}

// Re-nibble register layout LA -> LB through LDS, 2 rows at a time (37.9 KB).
template<int LA, int LB>
__device__ __forceinline__ void transpose(float (&x)[NROWS][16], int t, float* lds) {
    #pragma unroll
    for (int rg = 0; rg < 2; ++rg) {
        __syncthreads();  // protect previous reads before overwrite
        #pragma unroll
        for (int rh = 0; rh < 2; ++rh) {
            const int rr = rg * 2 + rh;
            float* base = lds + rh * LDS_STRIDE;
            if constexpr (LA == LAY_L) {
                const int a0 = pad_addr(t << 4);
                #pragma unroll
                for (int g = 0; g < 4; ++g) {
                    float4 wv;
                    wv.x = x[rr][4*g+0]; wv.y = x[rr][4*g+1];
                    wv.z = x[rr][4*g+2]; wv.w = x[rr][4*g+3];
                    *reinterpret_cast<float4*>(base + a0 + 4*g) = wv;
                }
            } else {
                #pragma unroll
                for (int v = 0; v < 16; ++v)
                    base[pad_addr(lay_q<LA>(t, v))] = x[rr][v];
            }
        }
        __syncthreads();
        #pragma unroll
        for (int rh = 0; rh < 2; ++rh) {
            const int rr = rg * 2 + rh;
            const float* base = lds + rh * LDS_STRIDE;
            if constexpr (LB == LAY_L) {
                const int a0 = pad_addr(t << 4);
                #pragma unroll
                for (int g = 0; g < 4; ++g) {
                    const float4 wv = *reinterpret_cast<const float4*>(base + a0 + 4*g);
                    x[rr][4*g+0] = wv.x; x[rr][4*g+1] = wv.y;
                    x[rr][4*g+2] = wv.z; x[rr][4*g+3] = wv.w;
                }
            } else {
                #pragma unroll
                for (int v = 0; v < 16; ++v)
                    x[rr][v] = base[pad_addr(lay_q<LB>(t, v))];
            }
        }
    }
}

// Build the PERMUTED stage-major table:
//   cs[(s<<11) | (h<<8) | t] = (cos, sin) of params[a(s,t,h)][s]
// where a(s,t,h) = ror12(tq,k) | ror12(v0<<NB,k) is exactly the index the
// old in-loop gather computed. (t,h) -> a is a bijection per stage since
// thread bits and nibble bits occupy disjoint positions before rotation.
__global__ void cs_kernel(const float* __restrict__ params, float2* __restrict__ cs) {
    const int i = blockIdx.x * blockDim.x + threadIdx.x;  // i = (s<<11)|(h<<8)|t
    const int s = i >> 11;
    const int h = (i >> 8) & 7;
    const int t = i & 255;
    const int r = s >> 2;
    const int j = s & 3;
    // round layouts: H M L H M L H MP
    int la;
    if (r == 1 || r == 4)      la = LAY_M;
    else if (r == 2 || r == 5) la = LAY_L;
    else if (r == 7)           la = LAY_MP;
    else                       la = LAY_H;
    const int NB = (la == LAY_H) ? 8 : (la == LAY_L) ? 0 : 4;
    int tq;
    if (la == LAY_H)       tq = t;
    else if (la == LAY_M)  tq = ((t & 0xF0) << 4) | (t & 15);
    else if (la == LAY_L)  tq = t << 4;
    else                   tq = ((t & 15) << 8) | (t >> 4);
    const int k  = NB + 4 - j;
    const int jb = 3 - j;
    const int v0 = ((h >> jb) << (jb + 1)) | (h & ((1 << jb) - 1));
    const int a  = ror12f(tq, k) | ror12f((v0 << NB) & 4095, k);
    const float th = params[(a << 5) | s];
    float sn, c;
    sincosf(th, &sn, &c);
    cs[i] = make_float2(c, sn);
}

__global__ void __launch_bounds__(NTH, 4)
butterfly_kernel(const float* __restrict__ X, const float2* __restrict__ cs,
                 float* __restrict__ out) {
    __shared__ __align__(16) float lds[2 * LDS_STRIDE];
    const int t = threadIdx.x;
    const long row0 = (long)blockIdx.x * NROWS;
    float x[NROWS][16];

    // initial load directly in H layout: q = (v<<8)|t, coalesced b32
    const float* Xp = X + row0 * WIDTH + t;
    #pragma unroll
    for (int rr = 0; rr < NROWS; ++rr)
        #pragma unroll
        for (int v = 0; v < 16; ++v)
            x[rr][v] = Xp[rr * WIDTH + (v << 8)];

    do_round<LAY_H,  0>(x, t, cs);
    transpose<LAY_H, LAY_M>(x, t, lds);
    do_round<LAY_M,  4>(x, t, cs);
    transpose<LAY_M, LAY_L>(x, t, lds);
    do_round<LAY_L,  8>(x, t, cs);
    transpose<LAY_L, LAY_H>(x, t, lds);
    do_round<LAY_H, 12>(x, t, cs);
    transpose<LAY_H, LAY_M>(x, t, lds);
    do_round<LAY_M, 16>(x, t, cs);
    transpose<LAY_M, LAY_L>(x, t, lds);
    do_round<LAY_L, 20>(x, t, cs);
    transpose<LAY_L, LAY_H>(x, t, lds);
    do_round<LAY_H, 24>(x, t, cs);
    transpose<LAY_H, LAY_MP>(x, t, lds);
    do_round<LAY_MP, 28>(x, t, cs);

    // round-7 layout was chosen so out column p = 16t + v: direct float4 stores
    float* op = out + row0 * WIDTH + (t << 4);
    #pragma unroll
    for (int rr = 0; rr < NROWS; ++rr)
        #pragma unroll
        for (int g = 0; g < 4; ++g) {
            float4 wv;
            wv.x = x[rr][4*g+0]; wv.y = x[rr][4*g+1];
            wv.z = x[rr][4*g+2]; wv.w = x[rr][4*g+3];
            *reinterpret_cast<float4*>(op + rr * WIDTH + 4*g) = wv;
        }
}

extern "C" void kernel_launch(void* const* d_in, const int* in_sizes, int n_in,
                              void* d_out, int out_size, void* d_ws, size_t ws_size,
                              hipStream_t stream) {
    (void)in_sizes; (void)n_in; (void)out_size; (void)ws_size;
    const float* X      = (const float*)d_in[0];
    const float* params = (const float*)d_in[1];
    float* out = (float*)d_out;
    float2* cs = (float2*)d_ws;   // 32*2048*8 B = 512 KB scratch

    hipLaunchKernelGGL(cs_kernel, dim3((HALF * DEPTH) / 256), dim3(256), 0, stream,
                       params, cs);
    hipLaunchKernelGGL(butterfly_kernel, dim3(BATCH / NROWS), dim3(NTH), 0, stream,
                       X, cs, out);
}